// Round 8
// baseline (269.872 us; speedup 1.0000x reference)
//
#include <hip/hip_runtime.h>

typedef __attribute__((ext_vector_type(8))) short short8;
typedef __attribute__((ext_vector_type(16))) float f32x16;

// ws layout:
//   Ft2  [z=512][yy=66][xx=66][8] bf16 halo-padded features, z = c*8 + b   (35.68 MB)
//   wt2  [i=576][n=128][8] bf16 B, i-major (i = c*9 + kh*3 + kw)           (1.18 MB)
#define FT2_SHORTS (512u * 4356u * 8u)
#define PLANE16    4356

__device__ __forceinline__ unsigned short f2bf(float x) {
    union { float f; unsigned u; } v; v.f = x;
    unsigned r = v.u + 0x7FFFu + ((v.u >> 16) & 1u);   // RNE bf16
    return (unsigned short)(r >> 16);
}

__device__ __forceinline__ void feat8(float p, unsigned short* uf) {
    float e   = __expf(-p);
    float sig = 1.f / (1.f + e);
    uf[0] = f2bf(p * sig);
    float u  = p * 1.5f + 4.5f;
    float fj = floorf(u);
    int   j0 = (int)fj;
    float t  = u - fj;
    bool  inr = (u >= 0.f) && (u < 9.f);
    float t2 = t * t, t3 = t2 * t;
    const float c16 = 1.f / 6.f;
    float r0 = t3 * c16;
    float r1 = (-3.f * t3 + 3.f * t2 + 3.f * t + 1.f) * c16;
    float r2 = (3.f * t3 - 6.f * t2 + 4.f) * c16;
    float s1 = 1.f - t;
    float r3 = s1 * s1 * s1 * c16;
#pragma unroll
    for (int g = 0; g < 6; ++g) {
        int r = j0 - g;
        float v = (r == 0) ? r0 : ((r == 1) ? r1 : ((r == 2) ? r2 : ((r == 3) ? r3 : 0.f)));
        uf[1 + g] = f2bf(inr ? v : 0.f);
    }
    uf[7] = 0;
}

// ---- Fused prep: per block (512): 144 B-chunks + 1 halo plane + 1 feature line ----
__global__ __launch_bounds__(256)
void prep_all(const float* __restrict__ x,
              const float* __restrict__ bw, const float* __restrict__ sw,
              unsigned short* __restrict__ ft, unsigned short* __restrict__ wt) {
    const int blk = blockIdx.x;          // 0..511
    const int tid = threadIdx.x;

    // (1) B prep into i-major layout: wt[i][n][8]
    if (tid < 144) {
        int idx = blk * 144 + tid;
        int o = idx / 576;
        int i = idx - o * 576;
        union { unsigned short u[8]; uint4 v; } pk;
        pk.u[0] = f2bf(bw[o * 576 + i]);
        const float* s = sw + (size_t)(o * 576 + i) * 6;
#pragma unroll
        for (int f = 0; f < 6; ++f) pk.u[1 + f] = f2bf(s[f]);
        pk.u[7] = 0;
        *(uint4*)(wt + ((size_t)i * 1024 + o * 8)) = pk.v;
    }

    // (2) halo plane z = blk: feat8(0) into the 260 border cells
    {
        short8 pad = { 0, 0, (short)0x3CAB, (short)0x3EF5,
                       (short)0x3EF5, (short)0x3CAB, 0, 0 };
        for (int t = tid; t < 260; t += 256) {
            int yy, xx;
            if (t < 66)       { yy = 0;       xx = t; }
            else if (t < 132) { yy = 65;      xx = t - 66; }
            else if (t < 196) { yy = t - 131; xx = 0; }
            else              { yy = t - 195; xx = 65; }
            ((short8*)ft)[blk * PLANE16 + yy * 66 + xx] = pad;
        }
    }

    // (3) features for line = blk (b = blk>>6, y = blk&63)
    __shared__ float Xl[64 * 65];
    const int b = blk >> 6, y = blk & 63;
    const float* xl = x + (size_t)blk * 4096;
    for (int f4 = tid; f4 < 1024; f4 += 256) {
        float4 v = ((const float4*)xl)[f4];
        int xx = f4 >> 4, c4 = (f4 & 15) << 2;
        float* d = &Xl[xx * 65 + c4];
        d[0] = v.x; d[1] = v.y; d[2] = v.z; d[3] = v.w;
    }
    __syncthreads();
    const int xx = tid & 63;
    const int cw = tid >> 6;
#pragma unroll 4
    for (int p = 0; p < 16; ++p) {
        int c = cw + (p << 2);
        float pv = Xl[xx * 65 + c];
        union { unsigned short u[8]; uint4 v; } pk;
        feat8(pv, pk.u);
        size_t o16 = (size_t)(c * 8 + b) * PLANE16 + (y + 1) * 66 + (xx + 1);
        *(uint4*)(ft + (o16 << 3)) = pk.v;
    }
}

// ---- Main GEMM: BARRIER-FREE all-register K-loop ----
// Diagnosis R0-R7: every barrier-phased schedule lands 57-70 us regardless of
// bytes/phase (fixed ~1 us per phase-wall x 72 walls). Fix: no phase walls.
// Each wave independently streams its MFMA fragments global->VGPR (4 x 16B/lane,
// coalesced, L2-hot) with a 2-step named-register rotation; compiler inserts
// counted vmcnt per data-dep. No LDS / s_barrier in the loop.
// Block 1024 = 16 waves (kq 0..3, mh, nh); tile 128px(2 lines) x 128n; wave
// 64px x 64n over K-quarter = c-pairs {kq, kq+4,..., kq+28} = 72 K16 steps.
// B addr linear in step (+4096 B); A: 9 per-lane (h-dep) step offsets + per-pair
// base bump. Epilogue: R3's 3-round LDS kq-reduction (barriers only there).
#define DZU 4460544u   // A base advance per c-pair step of 4 (dc=8 planes)

#define MFMA4(P)                                                                      \
    acc00 = __builtin_amdgcn_mfma_f32_32x32x16_bf16(P##a0, P##b0, acc00, 0, 0, 0);    \
    acc01 = __builtin_amdgcn_mfma_f32_32x32x16_bf16(P##a0, P##b1, acc01, 0, 0, 0);    \
    acc10 = __builtin_amdgcn_mfma_f32_32x32x16_bf16(P##a1, P##b0, acc10, 0, 0, 0);    \
    acc11 = __builtin_amdgcn_mfma_f32_32x32x16_bf16(P##a1, P##b1, acc11, 0, 0, 0);

#define ISS(P, CAX, S2)                                                               \
    P##a0 = *(const short8*)(ftc + (CAX) + aoff##S2);                                 \
    P##a1 = *(const short8*)(ftc + (CAX) + aoff##S2 + 512);                           \
    P##b0 = *(const short8*)(wtc + bv);                                               \
    P##b1 = *(const short8*)(wtc + bv + 512);                                         \
    bv += 4096u;

// One c-pair: 9 K16 steps, slots alternate SA,SB,...; issue depth = 2 steps.
#define PAIR(SA, SB, CAX, CAN, LAST)                                                  \
    MFMA4(SA) ISS(SA, CAX, 2)                                                         \
    MFMA4(SB) ISS(SB, CAX, 3)                                                         \
    MFMA4(SA) ISS(SA, CAX, 4)                                                         \
    MFMA4(SB) ISS(SB, CAX, 5)                                                         \
    MFMA4(SA) ISS(SA, CAX, 6)                                                         \
    MFMA4(SB) ISS(SB, CAX, 7)                                                         \
    MFMA4(SA) ISS(SA, CAX, 8)                                                         \
    bv += 110592u;  /* skip 3 c-pairs (stride-4 kq interleave) */                     \
    MFMA4(SB) if (!(LAST)) { ISS(SB, CAN, 0) }                                        \
    MFMA4(SA) if (!(LAST)) { ISS(SA, CAN, 1) }

#define MKAOFF(S)                                                                     \
    int aoff##S; {                                                                    \
        int t_ = 2 * (S) + h; int co_ = (t_ >= 9) ? 1 : 0; int j_ = t_ - 9 * co_;     \
        int kh_ = (j_ * 11) >> 5; int kw_ = j_ - kh_ * 3;                             \
        aoff##S = co_ * (8 * PLANE16 * 16) + (kh_ * 66 + kw_) * 16;                   \
    }

// Epilogue reduce helpers: conflict-free float4 layout (lane-stride 16 B).
#define DUMPA(base_, A_)                                                              \
    {   float4* s4 = (float4*)(red + (base_));                                        \
        _Pragma("unroll")                                                             \
        for (int c = 0; c < 4; ++c)                                                   \
            s4[c * 64 + lane] = make_float4(A_[4*c], A_[4*c+1], A_[4*c+2], A_[4*c+3]); }
#define ADDA(base_, A_)                                                               \
    {   const float4* s4 = (const float4*)(red + (base_));                            \
        _Pragma("unroll")                                                             \
        for (int c = 0; c < 4; ++c) {                                                 \
            float4 rv = s4[c * 64 + lane];                                            \
            A_[4*c] += rv.x; A_[4*c+1] += rv.y; A_[4*c+2] += rv.z; A_[4*c+3] += rv.w; } }

__global__ __launch_bounds__(1024, 4)
void convkan_gemm(const unsigned short* __restrict__ ft,
                  const unsigned short* __restrict__ wt,
                  const float* __restrict__ bias,
                  float* __restrict__ out) {
    __shared__ float red[16384];                 // 64 KB, epilogue only

    const int tid  = threadIdx.x;
    const int blk  = blockIdx.x;                 // 0..255
    const int mb   = ((blk & 7) << 5) | (blk >> 3);  // XCD swizzle: XCD owns image
    const int lane = tid & 63;
    const int wave = tid >> 6;                   // 0..15
    const int kq   = wave >> 2;                  // K-quarter (c-pair stride-4) 0..3
    const int mh   = (wave >> 1) & 1;            // line within 2-line tile
    const int nh   = wave & 1;                   // n-half (64 ch)
    const int l32  = lane & 31;
    const int h    = lane >> 5;                  // k-half within MFMA K16

    const int b  = mb >> 5;                      // image 0..7
    const int y0 = (mb & 31) << 1;               // first of 2 lines

    const char* ftc = (const char*)ft;
    const char* wtc = (const char*)wt;

    // per-lane step offsets (h-dependent), c-pair-relative
    MKAOFF(0) MKAOFF(1) MKAOFF(2) MKAOFF(3) MKAOFF(4)
    MKAOFF(5) MKAOFF(6) MKAOFF(7) MKAOFF(8)

    // running bases (32-bit byte offsets)
    unsigned cax = ((unsigned)((16 * kq + b) * PLANE16 + (y0 + mh) * 66 + l32)) << 4;
    unsigned can = cax + DZU;
    unsigned bv  = ((unsigned)(18 * kq + h) << 11) + (((unsigned)(nh * 64 + l32)) << 4);

    f32x16 acc00, acc01, acc10, acc11;
#pragma unroll
    for (int e = 0; e < 16; ++e) { acc00[e] = 0.f; acc01[e] = 0.f; acc10[e] = 0.f; acc11[e] = 0.f; }

    short8 Aa0, Aa1, Ab0, Ab1;                   // slot A
    short8 Ba0, Ba1, Bb0, Bb1;                   // slot B

    // prologue: issue steps 0,1 of c-pair 0
    ISS(A, cax, 0)
    ISS(B, cax, 1)

    // c-pairs 0..5 (parity alternates per pair; unroll pairs two at a time)
    for (int w = 0; w < 3; ++w) {
        PAIR(A, B, cax, can, 0) cax = can; can += DZU;
        PAIR(B, A, cax, can, 0) cax = can; can += DZU;
    }
    // c-pair 6 (issues pair 7 steps 0,1)
    PAIR(A, B, cax, can, 0) cax = can;
    // c-pair 7 (drain)
    PAIR(B, A, cax, cax, 1)

    // ---- K-partial reduction across kq (3 rounds via LDS), then store ----
    __syncthreads();
    const int grp = mh * 2 + nh;                 // 0..3

    if (kq >= 2) { DUMPA(((grp << 1) + (kq - 2)) * 2048,        acc00);
                   DUMPA(((grp << 1) + (kq - 2)) * 2048 + 1024, acc01); }
    __syncthreads();
    if (kq < 2)  { ADDA(((grp << 1) + kq) * 2048,        acc00);
                   ADDA(((grp << 1) + kq) * 2048 + 1024, acc01); }
    __syncthreads();
    if (kq >= 2) { DUMPA(((grp << 1) + (kq - 2)) * 2048,        acc10);
                   DUMPA(((grp << 1) + (kq - 2)) * 2048 + 1024, acc11); }
    __syncthreads();
    if (kq < 2)  { ADDA(((grp << 1) + kq) * 2048,        acc10);
                   ADDA(((grp << 1) + kq) * 2048 + 1024, acc11); }
    __syncthreads();
    if (kq == 1) { DUMPA(grp * 4096,        acc00); DUMPA(grp * 4096 + 1024, acc01);
                   DUMPA(grp * 4096 + 2048, acc10); DUMPA(grp * 4096 + 3072, acc11); }
    __syncthreads();
    if (kq == 0) {
        ADDA(grp * 4096,        acc00); ADDA(grp * 4096 + 1024, acc01);
        ADDA(grp * 4096 + 2048, acc10); ADDA(grp * 4096 + 3072, acc11);

        const int ncol = nh * 64 + l32;
        const float bv0 = bias[ncol];
        const float bv1 = bias[ncol + 32];
        const int prow = mb * 128 + mh * 64;
#pragma unroll
        for (int r = 0; r < 16; ++r) {
            int mrow = (r & 3) + ((r >> 2) << 3) + 4 * h;
            float* p = out + (size_t)(prow + mrow) * 128 + ncol;
            p[0]  = acc00[r] + bv0;
            p[32] = acc01[r] + bv1;
            float* p2 = out + (size_t)(prow + 32 + mrow) * 128 + ncol;
            p2[0]  = acc10[r] + bv0;
            p2[32] = acc11[r] + bv1;
        }
    }
}

extern "C" void kernel_launch(void* const* d_in, const int* in_sizes, int n_in,
                              void* d_out, int out_size, void* d_ws, size_t ws_size,
                              hipStream_t stream) {
    (void)in_sizes; (void)n_in; (void)ws_size; (void)out_size;
    const float* x        = (const float*)d_in[0];
    const float* base_w   = (const float*)d_in[1];
    const float* spline_w = (const float*)d_in[2];
    const float* bias     = (const float*)d_in[3];
    float* out = (float*)d_out;

    unsigned short* ft = (unsigned short*)d_ws;      // 35.68 MB halo features
    unsigned short* wt = ft + FT2_SHORTS;            // 1.18 MB tiled B (i-major)

    hipLaunchKernelGGL(prep_all, dim3(512), dim3(256), 0, stream,
                       x, base_w, spline_w, ft, wt);

    hipLaunchKernelGGL(convkan_gemm, dim3(256), dim3(1024), 0, stream,
                       ft, wt, bias, out);
}

// Round 9
// 141.400 us; speedup vs baseline: 1.9086x; 1.9086x over previous
//
#include <hip/hip_runtime.h>

typedef __attribute__((ext_vector_type(8))) short short8;
typedef __attribute__((ext_vector_type(16))) float f32x16;

// ws layout:
//   Ft2  [z=512][yy=66][xx=66][8] bf16 halo-padded features, z = c*8 + b   (35.68 MB)
//   wt2  [i=576][n=128][8] bf16 B, i-major (i = c*9 + kh*3 + kw)           (1.18 MB)
#define FT2_SHORTS (512u * 4356u * 8u)
#define PLANE16    4356

__device__ __forceinline__ unsigned short f2bf(float x) {
    union { float f; unsigned u; } v; v.f = x;
    unsigned r = v.u + 0x7FFFu + ((v.u >> 16) & 1u);   // RNE bf16
    return (unsigned short)(r >> 16);
}

__device__ __forceinline__ void feat8(float p, unsigned short* uf) {
    float e   = __expf(-p);
    float sig = 1.f / (1.f + e);
    uf[0] = f2bf(p * sig);
    float u  = p * 1.5f + 4.5f;
    float fj = floorf(u);
    int   j0 = (int)fj;
    float t  = u - fj;
    bool  inr = (u >= 0.f) && (u < 9.f);
    float t2 = t * t, t3 = t2 * t;
    const float c16 = 1.f / 6.f;
    float r0 = t3 * c16;
    float r1 = (-3.f * t3 + 3.f * t2 + 3.f * t + 1.f) * c16;
    float r2 = (3.f * t3 - 6.f * t2 + 4.f) * c16;
    float s1 = 1.f - t;
    float r3 = s1 * s1 * s1 * c16;
#pragma unroll
    for (int g = 0; g < 6; ++g) {
        int r = j0 - g;
        float v = (r == 0) ? r0 : ((r == 1) ? r1 : ((r == 2) ? r2 : ((r == 3) ? r3 : 0.f)));
        uf[1 + g] = f2bf(inr ? v : 0.f);
    }
    uf[7] = 0;
}

// ---- Fused prep: per block (512): 144 B-chunks + 1 halo plane + 1 feature line ----
__global__ __launch_bounds__(256)
void prep_all(const float* __restrict__ x,
              const float* __restrict__ bw, const float* __restrict__ sw,
              unsigned short* __restrict__ ft, unsigned short* __restrict__ wt) {
    const int blk = blockIdx.x;          // 0..511
    const int tid = threadIdx.x;

    // (1) B prep into i-major layout: wt[i][n][8]
    if (tid < 144) {
        int idx = blk * 144 + tid;
        int o = idx / 576;
        int i = idx - o * 576;
        union { unsigned short u[8]; uint4 v; } pk;
        pk.u[0] = f2bf(bw[o * 576 + i]);
        const float* s = sw + (size_t)(o * 576 + i) * 6;
#pragma unroll
        for (int f = 0; f < 6; ++f) pk.u[1 + f] = f2bf(s[f]);
        pk.u[7] = 0;
        *(uint4*)(wt + ((size_t)i * 1024 + o * 8)) = pk.v;
    }

    // (2) halo plane z = blk: feat8(0) into the 260 border cells
    {
        short8 pad = { 0, 0, (short)0x3CAB, (short)0x3EF5,
                       (short)0x3EF5, (short)0x3CAB, 0, 0 };
        for (int t = tid; t < 260; t += 256) {
            int yy, xx;
            if (t < 66)       { yy = 0;       xx = t; }
            else if (t < 132) { yy = 65;      xx = t - 66; }
            else if (t < 196) { yy = t - 131; xx = 0; }
            else              { yy = t - 195; xx = 65; }
            ((short8*)ft)[blk * PLANE16 + yy * 66 + xx] = pad;
        }
    }

    // (3) features for line = blk (b = blk>>6, y = blk&63)
    __shared__ float Xl[64 * 65];
    const int b = blk >> 6, y = blk & 63;
    const float* xl = x + (size_t)blk * 4096;
    for (int f4 = tid; f4 < 1024; f4 += 256) {
        float4 v = ((const float4*)xl)[f4];
        int xx = f4 >> 4, c4 = (f4 & 15) << 2;
        float* d = &Xl[xx * 65 + c4];
        d[0] = v.x; d[1] = v.y; d[2] = v.z; d[3] = v.w;
    }
    __syncthreads();
    const int xx = tid & 63;
    const int cw = tid >> 6;
#pragma unroll 4
    for (int p = 0; p < 16; ++p) {
        int c = cw + (p << 2);
        float pv = Xl[xx * 65 + c];
        union { unsigned short u[8]; uint4 v; } pk;
        feat8(pv, pk.u);
        size_t o16 = (size_t)(c * 8 + b) * PLANE16 + (y + 1) * 66 + (xx + 1);
        *(uint4*)(ft + (o16 << 3)) = pk.v;
    }
}

// ---- Main GEMM: BARRIER-FREE all-register K-loop, SPILL-PROOF config ----
// R8 retry with the register budget fixed: block 512 = 8 waves, launch_bounds
// (512,2) -> 2 waves/SIMD -> 256 unified regs/wave. Need ~120 (64 acc AGPR +
// 32 slot VGPR + 9 aoff + addressing) -> no spills (R8's 1024-thr config had a
// 128 budget and spilled 458 MB of scratch; counters, not structure, failed).
// Waves (kq 0..1, mh, nh): kq owns c-pairs {kq, kq+2, ..., kq+30} = 16 pairs
// x 9 K16 steps = 144 steps, 4 MFMA each. Fragments stream global->VGPR
// (4 x 16B/lane coalesced, L1/L2-hot; A reused 9x within a pair, nh/mh mirror
// waves hit L1). 2-step named-register rotation; no LDS/barriers in the loop.
// Epilogue: ONE LDS round (kq=1 dumps 64 KB, kq=0 adds + stores).
#define DZ2 2230272u   // A base advance per stride-2 c-pair (16 z-planes x 69696 B x 2)

#define MFMA4(P)                                                                      \
    acc00 = __builtin_amdgcn_mfma_f32_32x32x16_bf16(P##a0, P##b0, acc00, 0, 0, 0);    \
    acc01 = __builtin_amdgcn_mfma_f32_32x32x16_bf16(P##a0, P##b1, acc01, 0, 0, 0);    \
    acc10 = __builtin_amdgcn_mfma_f32_32x32x16_bf16(P##a1, P##b0, acc10, 0, 0, 0);    \
    acc11 = __builtin_amdgcn_mfma_f32_32x32x16_bf16(P##a1, P##b1, acc11, 0, 0, 0);

#define ISS(P, CAX, S2)                                                               \
    P##a0 = *(const short8*)(ftc + (CAX) + aoff##S2);                                 \
    P##a1 = *(const short8*)(ftc + (CAX) + aoff##S2 + 512);                           \
    P##b0 = *(const short8*)(wtc + bv);                                               \
    P##b1 = *(const short8*)(wtc + bv + 512);                                         \
    bv += 4096u;

// One c-pair: 9 K16 steps, slots alternate SA,SB,...; issue depth = 2 steps.
#define PAIR(SA, SB, CAX, CAN, LAST)                                                  \
    MFMA4(SA) ISS(SA, CAX, 2)                                                         \
    MFMA4(SB) ISS(SB, CAX, 3)                                                         \
    MFMA4(SA) ISS(SA, CAX, 4)                                                         \
    MFMA4(SB) ISS(SB, CAX, 5)                                                         \
    MFMA4(SA) ISS(SA, CAX, 6)                                                         \
    MFMA4(SB) ISS(SB, CAX, 7)                                                         \
    MFMA4(SA) ISS(SA, CAX, 8)                                                         \
    bv += 36864u;  /* skip 1 c-pair (stride-2 kq interleave) */                       \
    MFMA4(SB) if (!(LAST)) { ISS(SB, CAN, 0) }                                        \
    MFMA4(SA) if (!(LAST)) { ISS(SA, CAN, 1) }

#define MKAOFF(S)                                                                     \
    int aoff##S; {                                                                    \
        int t_ = 2 * (S) + h; int co_ = (t_ >= 9) ? 1 : 0; int j_ = t_ - 9 * co_;     \
        int kh_ = (j_ * 11) >> 5; int kw_ = j_ - kh_ * 3;                             \
        aoff##S = co_ * (8 * PLANE16 * 16) + (kh_ * 66 + kw_) * 16;                   \
    }

// Epilogue reduce helpers: conflict-free float4 layout (lane-stride 16 B).
#define DUMPA(base_, A_)                                                              \
    {   float4* s4 = (float4*)(red + (base_));                                        \
        _Pragma("unroll")                                                             \
        for (int c = 0; c < 4; ++c)                                                   \
            s4[c * 64 + lane] = make_float4(A_[4*c], A_[4*c+1], A_[4*c+2], A_[4*c+3]); }
#define ADDA(base_, A_)                                                               \
    {   const float4* s4 = (const float4*)(red + (base_));                            \
        _Pragma("unroll")                                                             \
        for (int c = 0; c < 4; ++c) {                                                 \
            float4 rv = s4[c * 64 + lane];                                            \
            A_[4*c] += rv.x; A_[4*c+1] += rv.y; A_[4*c+2] += rv.z; A_[4*c+3] += rv.w; } }

__global__ __launch_bounds__(512, 2)
void convkan_gemm(const unsigned short* __restrict__ ft,
                  const unsigned short* __restrict__ wt,
                  const float* __restrict__ bias,
                  float* __restrict__ out) {
    __shared__ float red[16384];                 // 64 KB, epilogue only

    const int tid  = threadIdx.x;
    const int blk  = blockIdx.x;                 // 0..255
    const int mb   = ((blk & 7) << 5) | (blk >> 3);  // XCD swizzle: XCD owns image
    const int lane = tid & 63;
    const int wave = tid >> 6;                   // 0..7
    const int kq   = wave >> 2;                  // K-half (c-pair stride-2) 0..1
    const int mh   = (wave >> 1) & 1;            // line within 2-line tile
    const int nh   = wave & 1;                   // n-half (64 ch)
    const int l32  = lane & 31;
    const int h    = lane >> 5;                  // k-half within MFMA K16

    const int b  = mb >> 5;                      // image 0..7
    const int y0 = (mb & 31) << 1;               // first of 2 lines

    const char* ftc = (const char*)ft;
    const char* wtc = (const char*)wt;

    // per-lane step offsets (h-dependent), c-pair-relative
    MKAOFF(0) MKAOFF(1) MKAOFF(2) MKAOFF(3) MKAOFF(4)
    MKAOFF(5) MKAOFF(6) MKAOFF(7) MKAOFF(8)

    // running bases (32-bit byte offsets)
    unsigned cax = ((unsigned)((16 * kq + b) * PLANE16 + (y0 + mh) * 66 + l32)) << 4;
    unsigned can = cax + DZ2;
    unsigned bv  = ((unsigned)(18 * kq + h) << 11) + (((unsigned)(nh * 64 + l32)) << 4);

    f32x16 acc00, acc01, acc10, acc11;
#pragma unroll
    for (int e = 0; e < 16; ++e) { acc00[e] = 0.f; acc01[e] = 0.f; acc10[e] = 0.f; acc11[e] = 0.f; }

    short8 Aa0, Aa1, Ab0, Ab1;                   // slot A
    short8 Ba0, Ba1, Bb0, Bb1;                   // slot B

    // prologue: issue steps 0,1 of c-pair kq
    ISS(A, cax, 0)
    ISS(B, cax, 1)

    // c-pairs 0..13 of this wave's 16 (parity alternates per pair)
    for (int w = 0; w < 7; ++w) {
        PAIR(A, B, cax, can, 0) cax = can; can += DZ2;
        PAIR(B, A, cax, can, 0) cax = can; can += DZ2;
    }
    // c-pair 14 (issues pair 15 steps 0,1)
    PAIR(A, B, cax, can, 0) cax = can;
    // c-pair 15 (drain)
    PAIR(B, A, cax, cax, 1)

    // ---- K-partial reduction across kq (ONE LDS round), then store ----
    __syncthreads();
    const int grp = mh * 2 + nh;                 // 0..3

    if (kq == 1) {
        DUMPA(grp * 4096,        acc00); DUMPA(grp * 4096 + 1024, acc01);
        DUMPA(grp * 4096 + 2048, acc10); DUMPA(grp * 4096 + 3072, acc11);
    }
    __syncthreads();
    if (kq == 0) {
        ADDA(grp * 4096,        acc00); ADDA(grp * 4096 + 1024, acc01);
        ADDA(grp * 4096 + 2048, acc10); ADDA(grp * 4096 + 3072, acc11);

        const int ncol = nh * 64 + l32;
        const float bv0 = bias[ncol];
        const float bv1 = bias[ncol + 32];
        const int prow = mb * 128 + mh * 64;
#pragma unroll
        for (int r = 0; r < 16; ++r) {
            int mrow = (r & 3) + ((r >> 2) << 3) + 4 * h;
            float* p = out + (size_t)(prow + mrow) * 128 + ncol;
            p[0]  = acc00[r] + bv0;
            p[32] = acc01[r] + bv1;
            float* p2 = out + (size_t)(prow + 32 + mrow) * 128 + ncol;
            p2[0]  = acc10[r] + bv0;
            p2[32] = acc11[r] + bv1;
        }
    }
}

extern "C" void kernel_launch(void* const* d_in, const int* in_sizes, int n_in,
                              void* d_out, int out_size, void* d_ws, size_t ws_size,
                              hipStream_t stream) {
    (void)in_sizes; (void)n_in; (void)ws_size; (void)out_size;
    const float* x        = (const float*)d_in[0];
    const float* base_w   = (const float*)d_in[1];
    const float* spline_w = (const float*)d_in[2];
    const float* bias     = (const float*)d_in[3];
    float* out = (float*)d_out;

    unsigned short* ft = (unsigned short*)d_ws;      // 35.68 MB halo features
    unsigned short* wt = ft + FT2_SHORTS;            // 1.18 MB tiled B (i-major)

    hipLaunchKernelGGL(prep_all, dim3(512), dim3(256), 0, stream,
                       x, base_w, spline_w, ft, wt);

    hipLaunchKernelGGL(convkan_gemm, dim3(256), dim3(512), 0, stream,
                       ft, wt, bias, out);
}